// Round 15
// baseline (747.223 us; speedup 1.0000x reference)
//
#include <hip/hip_runtime.h>
#include <hip/hip_bf16.h>
#include <stdint.h>

// GATv2Conv(1028->256, heads=1, self-loops) on gfx950, fp32 in/out.
// Pipeline: prep(hist-first | x->bf16 | W^T) -> coalesced 2-kernel scan ->
// scatter (own dispatch) -> bf16 MFMA GEMM (pure) -> fused gather.
// R19 post-mortem: merged gemm+scatter GREW to 243us (tail-placed scatter
// blocks run after gemm retires: serialization + contention, not overlap);
// serial sum of parts = 42 + <=145 = ~187 < 243. Ledger can't close while
// the merged kernel hides everything below 243.
// R20: de-merge. scatter standalone (attribution + expected ~55us win);
// gemm pure R2-form. prep/scan/gat unchanged from R19.

#define N_NODES 50000
#define N_EDGES 1600000
#define D_IN    1028
#define KPAD    1056   // D_IN padded to x32; xb/Wt zero-filled beyond 1028
#define D_OUT   256
#define NB      512    // xf row: cols [0,256)=xl, [256,512)=xr

// k_prep segments: hist FIRST (co-resident with x2b), then x2b, then Wt
#define HIST_GS    1024
#define X2B_GS     2048                     // grid-stride blocks for x->bf16
#define X2B_TOT    (N_NODES * 264)          // 4-col chunks: 1056/4 = 264 per row
#define WT_TILES   (33 * 8)                 // 32k x 64n tiles
#define PREP_BLOCKS (HIST_GS + X2B_GS + WT_TILES)

// coalesced scan
#define NBLK ((N_NODES + 255) / 256)        // 196

#define M_TILES 391                          // ceil(50000/128)
#define GEMM_MN (M_TILES * 4)                // 1564
#define SCAT_GS 2048

typedef __bf16 bf16x8 __attribute__((ext_vector_type(8)));
typedef float  f32x4  __attribute__((ext_vector_type(4)));

static __device__ __forceinline__ void gl_lds16(const void* g, void* l) {
  __builtin_amdgcn_global_load_lds(
      (const __attribute__((address_space(1))) unsigned int*)g,
      (__attribute__((address_space(3))) unsigned int*)l, 16, 0, 0);
}
static __device__ __forceinline__ unsigned short f2bf(float f) {
  union { float f; unsigned int i; } c; c.f = f;
  unsigned int r = 0x7fffu + ((c.i >> 16) & 1u);  // round-to-nearest-even
  return (unsigned short)((c.i + r) >> 16);
}

// ---------------- edge_index dtype autodetect --------------------------------
// mode==0 -> int64, mode!=0 -> int32.
__global__ void k_mode(const unsigned int* __restrict__ ei32, int* __restrict__ mode) {
  int t = blockIdx.x * 256 + threadIdx.x;  // 2048 probes
  if (t < 2048 && ei32[2 * t + 1] != 0u) atomicOr(mode, 1);
}

static __device__ __forceinline__ int load_idx(const int* ei, int md, int pos, int n) {
  int v = md ? ei[pos] : (int)((const long long*)ei)[pos];
  return v < 0 ? 0 : (v >= n ? n - 1 : v);
}

// ---------------- fused prep: hist | x->xb bf16 | W->Wt bf16 -----------------
__global__ __launch_bounds__(256) void k_prep(const float* __restrict__ x,
    const float* __restrict__ Wl, const float* __restrict__ Wr,
    const int* __restrict__ ei, const int* __restrict__ mode,
    unsigned short* __restrict__ xb, unsigned short* __restrict__ Wt,
    int* __restrict__ deg) {
  __shared__ unsigned short tile[32][66];  // pad 66: read-phase bank = k mod 32
  const int b = blockIdx.x, t = threadIdx.x;
  if (b < HIST_GS) {
    // degree histogram FIRST: co-resident with x2b, atomics hide under BW
    const int md = *mode;
    const int TH = HIST_GS * 256;
    for (int e = b * 256 + t; e < N_EDGES; e += TH) {
      int d = load_idx(ei, md, N_EDGES + e, N_NODES);
      atomicAdd(&deg[d], 1);
    }
  } else if (b < HIST_GS + X2B_GS) {
    // grid-stride over 4-col chunks; 4 independent loads in flight per thread.
    const int TH = X2B_GS * 256;
    for (int c = (b - HIST_GS) * 256 + t; c < X2B_TOT; c += 4 * TH) {
      int cc[4], rw[4], qq[4]; float4 v[4]; bool ld[4];
#pragma unroll
      for (int u = 0; u < 4; ++u) {
        cc[u] = c + u * TH;
        ld[u] = false; rw[u] = 0; qq[u] = 0;
        if (cc[u] < X2B_TOT) {
          rw[u] = cc[u] / 264;              // magic-mul
          qq[u] = cc[u] - rw[u] * 264;
          if (qq[u] < 257) {                // cols [0,1028): real data
            v[u] = *(const float4*)(x + (size_t)rw[u] * D_IN + 4 * qq[u]);
            ld[u] = true;
          }
        }
      }
#pragma unroll
      for (int u = 0; u < 4; ++u) {
        if (cc[u] < X2B_TOT) {
          ushort4 o = {0, 0, 0, 0};
          if (ld[u]) { o.x = f2bf(v[u].x); o.y = f2bf(v[u].y);
                       o.z = f2bf(v[u].z); o.w = f2bf(v[u].w); }
          *(ushort4*)(xb + (size_t)rw[u] * KPAD + 4 * qq[u]) = o;
        }
      }
    }
  } else {
    // LDS-tiled transpose: 32k x 64n tile, both global sides coalesced.
    const int w = b - HIST_GS - X2B_GS;
    const int k0 = (w >> 3) * 32, n0 = (w & 7) * 64;
#pragma unroll
    for (int j = 0; j < 8; ++j) {          // load: consecutive t -> consecutive n
      int k = 4 * j + (t >> 6), n = t & 63;
      unsigned short val = 0;
      if (k0 + k < D_IN) {
        int gn = n0 + n;
        val = f2bf(gn < D_OUT ? Wl[(size_t)(k0 + k) * D_OUT + gn]
                              : Wr[(size_t)(k0 + k) * D_OUT + (gn - D_OUT)]);
      }
      tile[k][n] = val;
    }
    __syncthreads();
#pragma unroll
    for (int j = 0; j < 8; ++j) {          // store: consecutive t -> consecutive k
      int n = 8 * j + (t >> 5), k = t & 31;
      Wt[(size_t)(n0 + n) * KPAD + k0 + k] = tile[k][n];
    }
  }
}

// ---------------- coalesced 2-kernel exclusive scan --------------------------
__global__ __launch_bounds__(256) void k_scansum(const int* __restrict__ deg,
    int* __restrict__ bsum, int n) {
  __shared__ int wsum[4];
  const int b = (int)blockIdx.x, t = (int)threadIdx.x;
  const int lane = t & 63, wid = t >> 6;
  int i = b * 256 + t;
  int v = (i < n) ? deg[i] : 0;
#pragma unroll
  for (int off = 32; off; off >>= 1) v += __shfl_xor(v, off, 64);
  if (lane == 0) wsum[wid] = v;
  __syncthreads();
  if (t == 0) bsum[b] = wsum[0] + wsum[1] + wsum[2] + wsum[3];
}
__global__ __launch_bounds__(256) void k_scanapply(const int* __restrict__ deg,
    const int* __restrict__ bsum, int* __restrict__ rowstart,
    int* __restrict__ cursor, int n) {
  __shared__ int bs[256];
  __shared__ int ws[4];
  const int b = (int)blockIdx.x, t = (int)threadIdx.x;
  const int lane = t & 63, wid = t >> 6;

  bs[t] = (t < NBLK) ? bsum[t] : 0;
  __syncthreads();
#pragma unroll
  for (int off = 1; off < 256; off <<= 1) {   // Hillis-Steele inclusive
    int v = bs[t] + ((t >= off) ? bs[t - off] : 0);
    __syncthreads();
    bs[t] = v;
    __syncthreads();
  }
  const int off_b = (b == 0) ? 0 : bs[b - 1];

  int i = b * 256 + t;
  int v = (i < n) ? deg[i] : 0;
  int x = v;                                  // wave inclusive scan
#pragma unroll
  for (int off = 1; off < 64; off <<= 1) {
    int y = __shfl_up(x, off, 64);
    if (lane >= off) x += y;
  }
  if (lane == 63) ws[wid] = x;
  __syncthreads();
  if (t < 4) {                                // exclusive scan of 4 wave sums
    int vv = ws[t], s = vv;
#pragma unroll
    for (int off = 1; off < 4; off <<= 1) {
      int y = __shfl_up(s, off, 4);
      if (t >= off) s += y;
    }
    ws[t] = s - vv;
  }
  __syncthreads();
  int excl = off_b + ws[wid] + (x - v);
  if (i < n) { rowstart[i] = excl; cursor[i] = excl; }
  if (b == 0 && t == 0) rowstart[n] = bs[NBLK - 1];
}

// ---------------- scatter (standalone for attribution) -----------------------
__global__ __launch_bounds__(256) void k_scatter(const int* __restrict__ ei,
    const int* __restrict__ mode, int* __restrict__ cursor,
    int* __restrict__ ssrc) {
  const int md = *mode;
  const int TH = SCAT_GS * 256;
  for (int e = (int)blockIdx.x * 256 + (int)threadIdx.x; e < N_EDGES; e += TH) {
    int s = load_idx(ei, md, e, N_NODES);
    int d = load_idx(ei, md, N_EDGES + e, N_NODES);
    int pos = atomicAdd(&cursor[d], 1);
    if (pos >= 0 && pos < N_EDGES) ssrc[pos] = s;
  }
}

// ---------------- GEMM (pure R2-form, bf16 gl_lds) ---------------------------
// 128x128 tile, BK=32, 16x16x32 mfma, 4 waves 64x64 each.
__global__ __launch_bounds__(256) void k_gemm(const unsigned short* __restrict__ xb,
    const unsigned short* __restrict__ Wt, unsigned short* __restrict__ xf, int M) {
  __shared__ unsigned short smem[16896];  // As[0,4096) Bs[4096,8192); Cs overlays
  unsigned short* As = smem;
  unsigned short* Bs = smem + 4096;
  unsigned short* Cs = smem;
  const int bid = (int)blockIdx.x;
  const int tid = threadIdx.x;
  const int w = tid >> 6, lane = tid & 63;
  const int m0 = (bid % M_TILES) * 128, n0 = (bid / M_TILES) * 128;
  const int wm = (w >> 1) * 64, wn = (w & 1) * 64;

  f32x4 zero = {0.f, 0.f, 0.f, 0.f};
  f32x4 acc[4][4];
#pragma unroll
  for (int i = 0; i < 4; ++i)
#pragma unroll
    for (int j = 0; j < 4; ++j) acc[i][j] = zero;

  const int lrow = lane >> 2, lch = lane & 3;  // 16 rows x 4 x16B chunks / call

  for (int k0 = 0; k0 < KPAD; k0 += 32) {
    __syncthreads();
#pragma unroll
    for (int j = 0; j < 2; ++j) {
      int gm = m0 + w * 32 + j * 16 + lrow;
      if (gm >= M) gm = M - 1;
      const char* g = (const char*)xb + ((size_t)gm * KPAD + k0) * 2 + lch * 16;
      gl_lds16(g, &As[(w * 32 + j * 16) * 32]);
    }
#pragma unroll
    for (int j = 0; j < 2; ++j) {
      int gn = n0 + w * 32 + j * 16 + lrow;
      const char* g = (const char*)Wt + ((size_t)gn * KPAD + k0) * 2 + lch * 16;
      gl_lds16(g, &Bs[(w * 32 + j * 16) * 32]);
    }
    __syncthreads();

    bf16x8 af[4], bfr[4];
#pragma unroll
    for (int t = 0; t < 4; ++t)
      af[t] = *(const bf16x8*)&As[(wm + t * 16 + (lane & 15)) * 32 + (lane >> 4) * 8];
#pragma unroll
    for (int t = 0; t < 4; ++t)
      bfr[t] = *(const bf16x8*)&Bs[(wn + t * 16 + (lane & 15)) * 32 + (lane >> 4) * 8];
#pragma unroll
    for (int mt = 0; mt < 4; ++mt)
#pragma unroll
      for (int nt = 0; nt < 4; ++nt)
        acc[mt][nt] = __builtin_amdgcn_mfma_f32_16x16x32_bf16(af[mt], bfr[nt], acc[mt][nt], 0, 0, 0);
  }

  // C/D layout: col = lane&15, row = (lane>>4)*4 + r
  __syncthreads();  // all As/Bs reads done before Cs overlay
  {
    const int col = lane & 15, rq = (lane >> 4) * 4;
#pragma unroll
    for (int mt = 0; mt < 4; ++mt)
#pragma unroll
      for (int nt = 0; nt < 4; ++nt)
#pragma unroll
        for (int r = 0; r < 4; ++r)
          Cs[(wm + mt * 16 + rq + r) * 132 + wn + nt * 16 + col] = f2bf(acc[mt][nt][r]);
  }
  __syncthreads();
  {
    const int row = tid >> 1, half = tid & 1;  // 2 threads per row, 128B each
    int gm = m0 + row;
    if (gm < M) {
      unsigned short* dst = xf + (size_t)gm * NB + n0 + half * 64;
      const unsigned short* srcp = &Cs[row * 132 + half * 64];
#pragma unroll
      for (int j = 0; j < 8; ++j)
        *(uint4*)(dst + j * 8) = *(const uint4*)(srcp + j * 8);
    }
  }
}

// ---------------- fused gather + online softmax + aggregate ------------------
// Wave = 2 groups x 32 lanes; lane covers dims [8*gl, 8*gl+8); depth-2;
// defer-rescale (e<=m group-uniform path skips acc rescale).
static __device__ __forceinline__ void unpack8(uint4 u, float* v) {
  union { unsigned int i; float f; } c;
  c.i = u.x << 16;         v[0] = c.f;
  c.i = u.x & 0xffff0000u; v[1] = c.f;
  c.i = u.y << 16;         v[2] = c.f;
  c.i = u.y & 0xffff0000u; v[3] = c.f;
  c.i = u.z << 16;         v[4] = c.f;
  c.i = u.z & 0xffff0000u; v[5] = c.f;
  c.i = u.w << 16;         v[6] = c.f;
  c.i = u.w & 0xffff0000u; v[7] = c.f;
}
static __device__ __forceinline__ float dot8(const float* v, const float* xr, const float* a) {
  float e = 0.f;
#pragma unroll
  for (int d = 0; d < 8; ++d) {
    float t = v[d] + xr[d];
    t = fmaxf(t, 0.2f * t);        // LeakyReLU(0.2)
    e = fmaf(a[d], t, e);
  }
  return e;
}
static __device__ __forceinline__ float red32(float e) {
#pragma unroll
  for (int off = 1; off < 32; off <<= 1) e += __shfl_xor(e, off, 64);
  return e;
}

__global__ __launch_bounds__(256) void k_gat(const unsigned short* __restrict__ xf,
    const int* __restrict__ rowstart, const int* __restrict__ ssrc,
    const float* __restrict__ att, const float* __restrict__ bias,
    float* __restrict__ out, int n) {
  const int gw = (int)blockIdx.x * 4 + (int)(threadIdx.x >> 6);  // 1 wave/dst
  const int lane = (int)(threadIdx.x & 63);
  const int grp = lane >> 5, gl = lane & 31;
  if (gw >= n) return;

  float a[8];
  {
    float4 A0 = ((const float4*)att)[2 * gl];
    float4 A1 = ((const float4*)att)[2 * gl + 1];
    a[0] = A0.x; a[1] = A0.y; a[2] = A0.z; a[3] = A0.w;
    a[4] = A1.x; a[5] = A1.y; a[6] = A1.z; a[7] = A1.w;
  }
  float xr[8], vs[8];
  unpack8(*(const uint4*)(xf + (size_t)gw * NB + D_OUT + 8 * gl), xr);
  unpack8(*(const uint4*)(xf + (size_t)gw * NB + 8 * gl), vs);   // self row (xl)

  // self-loop into group 0; group 1 starts empty
  float m, l, acc[8];
  {
    float e = red32(dot8(vs, xr, a));
    if (grp == 0) {
      m = e; l = 1.f;
#pragma unroll
      for (int d = 0; d < 8; ++d) acc[d] = vs[d];
    } else {
      m = -1e30f; l = 0.f;
#pragma unroll
      for (int d = 0; d < 8; ++d) acc[d] = 0.f;
    }
  }

  const int end = rowstart[gw + 1];
  int i = rowstart[gw] + grp;                     // group g: edges beg+g, +2, ...
  bool have = i < end;
  uint4 vu;
  if (have) {
    unsigned s = (unsigned)ssrc[i];
    vu = *(const uint4*)(xf + ((size_t)s << 9) + 8 * gl);
  }
  while (have) {
    int i2 = i + 2;
    bool have2 = i2 < end;
    uint4 vu2;
    if (have2) {                                  // depth-2 pipeline: prefetch
      unsigned s2 = (unsigned)ssrc[i2];
      vu2 = *(const uint4*)(xf + ((size_t)s2 << 9) + 8 * gl);
    }
    float v[8];
    unpack8(vu, v);
    float e = red32(dot8(v, xr, a));
    if (e <= m) {                                 // common: max unchanged
      float p = __expf(e - m);
#pragma unroll
      for (int d = 0; d < 8; ++d) acc[d] = fmaf(p, v[d], acc[d]);
      l += p;
    } else {                                      // new max: p = 1
      float sc = __expf(m - e);
#pragma unroll
      for (int d = 0; d < 8; ++d) acc[d] = fmaf(acc[d], sc, v[d]);
      l = fmaf(l, sc, 1.f);
      m = e;
    }
    vu = vu2; i = i2; have = have2;
  }

  // flash-merge the two groups (lane L and L+32 hold the same dims)
  float mo = __shfl_xor(m, 32, 64);
  float mM = fmaxf(m, mo);
  float sA = __expf(m - mM);
  float lA = l * sA;
  float lS = lA + __shfl_xor(lA, 32, 64);
  float inv = 1.f / lS;
#pragma unroll
  for (int d = 0; d < 8; ++d) {
    float t = acc[d] * sA;
    acc[d] = t + __shfl_xor(t, 32, 64);
  }
  if (grp == 0) {
    float4 B0 = ((const float4*)bias)[2 * gl];
    float4 B1 = ((const float4*)bias)[2 * gl + 1];
    float4 o0, o1;
    o0.x = fmaf(acc[0], inv, B0.x); o0.y = fmaf(acc[1], inv, B0.y);
    o0.z = fmaf(acc[2], inv, B0.z); o0.w = fmaf(acc[3], inv, B0.w);
    o1.x = fmaf(acc[4], inv, B1.x); o1.y = fmaf(acc[5], inv, B1.y);
    o1.z = fmaf(acc[6], inv, B1.z); o1.w = fmaf(acc[7], inv, B1.w);
    ((float4*)out)[(size_t)gw * 64 + 2 * gl] = o0;
    ((float4*)out)[(size_t)gw * 64 + 2 * gl + 1] = o1;
  }
}

// ---------------- launch -----------------------------------------------------
extern "C" void kernel_launch(void* const* d_in, const int* in_sizes, int n_in,
                              void* d_out, int out_size, void* d_ws, size_t ws_size,
                              hipStream_t stream) {
  (void)in_sizes; (void)n_in; (void)out_size; (void)ws_size;
  const float* x   = (const float*)d_in[0];
  const int*   ei  = (const int*)d_in[1];
  const float* Wl  = (const float*)d_in[2];
  const float* Wr  = (const float*)d_in[3];
  const float* att = (const float*)d_in[4];
  const float* bia = (const float*)d_in[5];
  float* out = (float*)d_out;

  const int N = N_NODES;
  const int E = N_EDGES;

  char* ws = (char*)d_ws;
  size_t off = 0;
  unsigned short* xb = (unsigned short*)(ws + off); off += (size_t)N * KPAD * 2;  // 105.6 MB
  unsigned short* xf = (unsigned short*)(ws + off); off += (size_t)N * NB * 2;    //  51.2 MB
  unsigned short* Wt = (unsigned short*)(ws + off); off += (size_t)NB * KPAD * 2; //   1.1 MB
  off = (off + 255) & ~(size_t)255;
  int* deg      = (int*)(ws + off); off += (size_t)N * 4;
  int* mode     = (int*)(ws + off); off += 256;   // adjacent to deg: one memset
  int* bsum     = (int*)(ws + off); off += (size_t)NBLK * 4;
  off = (off + 255) & ~(size_t)255;
  int* rowstart = (int*)(ws + off); off += (size_t)(N + 1) * 4;
  off = (off + 255) & ~(size_t)255;
  int* cursor   = (int*)(ws + off); off += (size_t)N * 4;
  int* ssrc     = (int*)(ws + off); off += (size_t)E * 4;   // total ~165 MB

  hipMemsetAsync(deg, 0, (size_t)N * 4 + 256, stream);      // deg + mode
  k_mode<<<8, 256, 0, stream>>>((const unsigned int*)ei, mode);
  k_prep<<<PREP_BLOCKS, 256, 0, stream>>>(x, Wl, Wr, ei, mode, xb, Wt, deg);
  k_scansum<<<NBLK, 256, 0, stream>>>(deg, bsum, N);
  k_scanapply<<<NBLK, 256, 0, stream>>>(deg, bsum, rowstart, cursor, N);
  k_scatter<<<SCAT_GS, 256, 0, stream>>>(ei, mode, cursor, ssrc);
  k_gemm<<<GEMM_MN, 256, 0, stream>>>(xb, Wt, xf, N);
  k_gat<<<(N + 3) / 4, 256, 0, stream>>>(xf, rowstart, ssrc, att, bia, out, N);
}